// Round 6
// baseline (409.032 us; speedup 1.0000x reference)
//
#include <hip/hip_runtime.h>

#define EPSBN 1e-3f

typedef unsigned short ushort_t;
typedef __attribute__((ext_vector_type(8))) short bf8;   // 8 bf16 = 4 VGPRs
typedef __attribute__((ext_vector_type(4))) float f4;

__device__ __forceinline__ float sigmoidf_(float z) {
  return 1.0f / (1.0f + expf(-z));
}

__device__ __forceinline__ ushort_t f2bf(float x) {  // RTNE
  union { float f; unsigned u; } v; v.f = x;
  unsigned r = (v.u + 0x7fffu + ((v.u >> 16) & 1u)) >> 16;
  return (ushort_t)r;
}

// 8-block per-batch barrier. ctr starts at 0 (memset node); call i has target 8*i.
__device__ __forceinline__ void batch_barrier(unsigned* ctr, unsigned target) {
  __syncthreads();
  if (threadIdx.x == 0) {
    __threadfence();                 // release: prior writes visible device-wide
    atomicAdd(ctr, 1u);
    while (atomicAdd(ctr, 0u) < target) __builtin_amdgcn_s_sleep(2);
    __threadfence();                 // acquire side
  }
  __syncthreads();
}

// ---------------- THE fused kernel: 512 blocks x 256 threads, cooperative -----
__global__ __launch_bounds__(256, 2)
void k_fused(const float* __restrict__ x,
             const float* __restrict__ experts1,
             const float* __restrict__ rw1, const float* __restrict__ rb1,
             const float* __restrict__ g1, const float* __restrict__ be1,
             const float* __restrict__ mu1, const float* __restrict__ va1,
             const float* __restrict__ sw1a, const float* __restrict__ sw1b,
             const float* __restrict__ experts2,
             const float* __restrict__ rw2, const float* __restrict__ rb2,
             const float* __restrict__ g2, const float* __restrict__ be2,
             const float* __restrict__ mu2, const float* __restrict__ va2,
             const float* __restrict__ sw2a, const float* __restrict__ sw2b,
             const float* __restrict__ experts3,
             const float* __restrict__ rw3, const float* __restrict__ rb3,
             const float* __restrict__ g3, const float* __restrict__ be3,
             const float* __restrict__ mu3, const float* __restrict__ va3,
             float* __restrict__ out,
             float* __restrict__ meanx_part, float* __restrict__ part_m1,
             ushort_t* __restrict__ k2pb, float* __restrict__ part_s3,
             ushort_t* __restrict__ p1b, unsigned* __restrict__ bctr) {
  __shared__ __align__(16) unsigned char smem[53568];
  const int bid = blockIdx.x;
  const int b = bid >> 3;
  const int sub = bid & 7;
  const int tid = threadIdx.x;
  unsigned* ctr = bctr + b;

  // ---------------- Phase 0: mean_x partial (this block's eighth) --------------
  {
    float acc[6] = {0.f, 0.f, 0.f, 0.f, 0.f, 0.f};
    const float* base = x + (size_t)b * 98304 + (size_t)sub * 12288 + (size_t)tid * 48;
#pragma unroll
    for (int k = 0; k < 12; ++k) {
      const float4 v = *(const float4*)(base + k * 4);
      acc[(4 * k + 0) % 6] += v.x;
      acc[(4 * k + 1) % 6] += v.y;
      acc[(4 * k + 2) % 6] += v.z;
      acc[(4 * k + 3) % 6] += v.w;
    }
#pragma unroll
    for (int c = 0; c < 6; ++c)
      for (int off = 32; off > 0; off >>= 1) acc[c] += __shfl_down(acc[c], off, 64);
    float* red0 = (float*)smem;  // [4][6]
    const int lane = tid & 63, w = tid >> 6;
    if (lane == 0) {
#pragma unroll
      for (int c = 0; c < 6; ++c) red0[w * 6 + c] = acc[c];
    }
    __syncthreads();
    if (tid < 6)
      meanx_part[bid * 6 + tid] = red0[tid] + red0[6 + tid] + red0[12 + tid] + red0[18 + tid];
  }
  batch_barrier(ctr, 8u);

  // ---------------- Phase 1: conv1 MFMA + BN + relu + pool + mean1 partial -----
  {
    ushort_t* patch = (ushort_t*)smem;                   // 34*68*8 = 36,992 B
    float* route_s = (float*)(smem + 36992);             // 3 (+1 pad)
    float* mred = (float*)(smem + 37008);                // [4][32]
    const int tyi = sub >> 1, txi = sub & 1;
    const float* xb = x + (size_t)b * 98304;

    if (tid < 3) {
      float z = rb1[tid];
      for (int c = 0; c < 6; ++c) {
        float s = 0.f;
#pragma unroll
        for (int k = 0; k < 8; ++k) s += meanx_part[(b * 8 + k) * 6 + c];
        z += (s * (1.0f / 16384.0f)) * rw1[c * 3 + tid];
      }
      route_s[tid] = sigmoidf_(z);
    }

    for (int v = tid; v < 34 * 68; v += 256) {
      const int ry = v / 68, p = v - ry * 68;
      const int gy = tyi * 32 - 1 + ry, gx = txi * 64 - 1 + p;
      uint4 u = make_uint4(0u, 0u, 0u, 0u);
      if (((unsigned)gy < 128u) && ((unsigned)gx < 128u)) {
        const float* s = xb + ((size_t)(gy * 128 + gx)) * 6;
        const float2 a0 = *(const float2*)s;
        const float2 a1 = *(const float2*)(s + 2);
        const float2 a2 = *(const float2*)(s + 4);
        u.x = (unsigned)f2bf(a0.x) | ((unsigned)f2bf(a0.y) << 16);
        u.y = (unsigned)f2bf(a1.x) | ((unsigned)f2bf(a1.y) << 16);
        u.z = (unsigned)f2bf(a2.x) | ((unsigned)f2bf(a2.y) << 16);
        u.w = 0u;
      }
      *(uint4*)(patch + (size_t)v * 8) = u;
    }
    __syncthreads();

    const int w = tid >> 6;
    const int lane = tid & 63;
    const int lx = lane & 15, lg = lane >> 4;

    const float r0 = route_s[0], r1 = route_s[1], r2 = route_s[2];
    const int co0 = lx, co1 = 16 + lx;
    const float inv0 = g1[co0] * rsqrtf(va1[co0] + EPSBN);
    const float bias0 = be1[co0] - mu1[co0] * inv0;
    const float inv1 = g1[co1] * rsqrtf(va1[co1] + EPSBN);
    const float bias1 = be1[co1] - mu1[co1] * inv1;

    bf8 Bf[3][2];
#pragma unroll
    for (int ky = 0; ky < 3; ++ky) {
#pragma unroll
      for (int nt = 0; nt < 2; ++nt) {
        const int co = nt * 16 + lx;
        const float inv = nt ? inv1 : inv0;
#pragma unroll
        for (int j = 0; j < 8; ++j) {
          float val = 0.f;
          if (j < 6 && lg < 3) {
            const int idx = ((ky * 3 + lg) * 6 + j) * 32 + co;
            val = (r0 * experts1[idx] + r1 * experts1[1728 + idx] +
                   r2 * experts1[3456 + idx]) * inv;
          }
          Bf[ky][nt][j] = (short)f2bf(val);
        }
      }
    }

    float msum0 = 0.f, msum1 = 0.f;
#pragma unroll
    for (int xt = 0; xt < 4; ++xt) {
      bf8 Af[10];
#pragma unroll
      for (int r = 0; r < 10; ++r)
        Af[r] = *(const bf8*)(patch + ((size_t)(w * 8 + r) * 68 + xt * 16 + lx + lg) * 8);
#pragma unroll
      for (int rp = 0; rp < 4; ++rp) {
        const int prow = tyi * 16 + w * 4 + rp;
        f4 acc0[2], acc1[2];
#pragma unroll
        for (int nt = 0; nt < 2; ++nt) {
          acc0[nt] = (f4){0.f, 0.f, 0.f, 0.f};
          acc1[nt] = (f4){0.f, 0.f, 0.f, 0.f};
        }
#pragma unroll
        for (int ky = 0; ky < 3; ++ky) {
#pragma unroll
          for (int nt = 0; nt < 2; ++nt) {
            acc0[nt] = __builtin_amdgcn_mfma_f32_16x16x32_bf16(Af[rp * 2 + ky], Bf[ky][nt], acc0[nt], 0, 0, 0);
            acc1[nt] = __builtin_amdgcn_mfma_f32_16x16x32_bf16(Af[rp * 2 + ky + 1], Bf[ky][nt], acc1[nt], 0, 0, 0);
          }
        }
#pragma unroll
        for (int nt = 0; nt < 2; ++nt) {
          const float bias = nt ? bias1 : bias0;
          const int co = nt * 16 + lx;
#pragma unroll
          for (int q = 0; q < 2; ++q) {
            const float m0 = fmaxf(acc0[nt][2 * q] + bias, 0.f);
            const float m1 = fmaxf(acc0[nt][2 * q + 1] + bias, 0.f);
            const float m2 = fmaxf(acc1[nt][2 * q] + bias, 0.f);
            const float m3 = fmaxf(acc1[nt][2 * q + 1] + bias, 0.f);
            const float mx = fmaxf(fmaxf(m0, m1), fmaxf(m2, m3));
            if (nt) msum1 += mx; else msum0 += mx;
            const int pcol = txi * 32 + xt * 8 + lg * 2 + q;
            p1b[(((size_t)b * 64 + prow) * 64 + pcol) * 32 + co] = f2bf(mx);
          }
        }
      }
    }

    msum0 += __shfl_xor(msum0, 16, 64);
    msum0 += __shfl_xor(msum0, 32, 64);
    msum1 += __shfl_xor(msum1, 16, 64);
    msum1 += __shfl_xor(msum1, 32, 64);
    if (lg == 0) {
      mred[w * 32 + lx] = msum0;
      mred[w * 32 + 16 + lx] = msum1;
    }
    __syncthreads();
    if (tid < 32) {
      part_m1[(size_t)bid * 32 + tid] =
          mred[tid] + mred[32 + tid] + mred[64 + tid] + mred[96 + tid];
    }
  }
  batch_barrier(ctr, 16u);

  // ---------------- Phase 2: SE1 + route2 + build k2' (this block's slice) -----
  {
    float* m1 = (float*)smem;          // 32
    float* h = m1 + 32;                // 2 (+pad)
    float* s1 = h + 4;                 // 32
    float* route = s1 + 32;            // 3
    if (tid < 32) {
      float s = 0.f;
#pragma unroll
      for (int k = 0; k < 8; ++k) s += part_m1[(size_t)(b * 8 + k) * 32 + tid];
      m1[tid] = s * (1.0f / 4096.0f);
    }
    __syncthreads();
    if (tid < 2) {
      float z = 0.f;
      for (int c = 0; c < 32; ++c) z += m1[c] * sw1a[c * 2 + tid];
      h[tid] = fmaxf(z, 0.f);
    }
    __syncthreads();
    if (tid < 32) s1[tid] = sigmoidf_(h[0] * sw1b[tid] + h[1] * sw1b[32 + tid]);
    __syncthreads();
    if (tid < 3) {
      float z = rb2[tid];
      for (int c = 0; c < 32; ++c) z += m1[c] * s1[c] * rw2[c * 3 + tid];
      route[tid] = sigmoidf_(z);
    }
    __syncthreads();
    const float r0 = route[0], r1 = route[1], r2 = route[2];
    const int t_lo = sub * 2304, t_hi = t_lo + 2304;
    for (int t = t_lo + tid; t < t_hi; t += 256) {
      const int co = t & 63;
      const int ci = (t >> 6) & 31;
      const int tap = t >> 11;
      const float inv = g2[co] * rsqrtf(va2[co] + EPSBN);
      const float v = r0 * experts2[t] + r1 * experts2[18432 + t] + r2 * experts2[2 * 18432 + t];
      k2pb[(size_t)b * 18432 + ((size_t)tap * 64 + co) * 32 + ci] = f2bf(v * s1[ci] * inv);
    }
  }
  batch_barrier(ctr, 24u);

  // ---------------- Phase 3: conv2 x4 tiles, S3 boundary aggregates ------------
  {
    short* As = (short*)smem;                 // 12960 shorts
    short* Bs = As + 12960;                   // 11520 shorts
    float* sred = (float*)(smem + 48960);     // 1152 floats
    const int w = tid >> 6;
    const int lane = tid & 63;
    const int lx = lane & 15, lg = lane >> 4;
    const ushort_t* pb = p1b + (size_t)b * 131072;

    for (int cc = 0; cc < 4; ++cc) {
      const int ti = sub * 4 + cc;
      const int tile = ti >> 1, cog = ti & 1;
      const int ty = tile >> 2, tx2 = tile & 3;
      __syncthreads();
      for (int v = tid; v < 1296; v += 256) {
        const int cell = v >> 2, part = v & 3;
        const int ly = cell / 18, lx2 = cell - ly * 18;
        const int gy = ty * 16 - 1 + ly, gx = tx2 * 16 - 1 + lx2;
        uint4 d = make_uint4(0u, 0u, 0u, 0u);
        if (((unsigned)gy < 64u) && ((unsigned)gx < 64u))
          d = *(const uint4*)(pb + (((size_t)gy << 6) + gx) * 32 + part * 8);
        *(uint4*)(As + (ly * 18 + lx2) * 40 + part * 8) = d;
      }
      for (int v = tid; v < 1152; v += 256) {
        const int r = v >> 2, part = v & 3;
        const int t = r >> 5, n = r & 31;
        const uint4 d = *(const uint4*)(k2pb + (size_t)b * 18432 +
                                        ((size_t)(t * 64 + cog * 32 + n)) * 32 + part * 8);
        *(uint4*)(Bs + r * 40 + part * 8) = d;
      }
      __syncthreads();

      f4 acc[4][2];
#pragma unroll
      for (int mt = 0; mt < 4; ++mt)
#pragma unroll
        for (int nt = 0; nt < 2; ++nt)
          acc[mt][nt] = (f4){0.f, 0.f, 0.f, 0.f};

#pragma unroll
      for (int kx = 0; kx < 3; ++kx) {
        bf8 Af[6];
#pragma unroll
        for (int r = 0; r < 6; ++r)
          Af[r] = *(const bf8*)(As + ((4 * w + r) * 18 + lx + kx) * 40 + (lg << 3));
#pragma unroll
        for (int ky = 0; ky < 3; ++ky) {
          const int t = ky * 3 + kx;
          const bf8 Bf0 = *(const bf8*)(Bs + ((t << 5) + lx) * 40 + (lg << 3));
          const bf8 Bf1 = *(const bf8*)(Bs + ((t << 5) + 16 + lx) * 40 + (lg << 3));
#pragma unroll
          for (int mt = 0; mt < 4; ++mt) {
            acc[mt][0] = __builtin_amdgcn_mfma_f32_16x16x32_bf16(Af[ky + mt], Bf0, acc[mt][0], 0, 0, 0);
            acc[mt][1] = __builtin_amdgcn_mfma_f32_16x16x32_bf16(Af[ky + mt], Bf1, acc[mt][1], 0, 0, 0);
          }
        }
      }

      float inv[2], bias[2];
#pragma unroll
      for (int nt = 0; nt < 2; ++nt) {
        const int co = cog * 32 + nt * 16 + lx;
        inv[nt] = g2[co] * rsqrtf(va2[co] + EPSBN);
        bias[nt] = be2[co] - mu2[co] * inv[nt];
      }
      float agg[2][9];
#pragma unroll
      for (int nt = 0; nt < 2; ++nt)
#pragma unroll
        for (int a = 0; a < 9; ++a) agg[nt][a] = 0.f;

#pragma unroll
      for (int half = 0; half < 2; ++half) {
        const int prow = ty * 8 + 2 * w + half;
        const bool rT = (prow == 0), rB = (prow == 31);
#pragma unroll
        for (int q = 0; q < 2; ++q) {
          const int pcol = tx2 * 8 + 2 * lg + q;
          const bool cL = (pcol == 0), cR = (pcol == 31);
#pragma unroll
          for (int nt = 0; nt < 2; ++nt) {
            const float m0 = fmaxf(acc[2 * half][nt][2 * q] + bias[nt], 0.f);
            const float m1 = fmaxf(acc[2 * half][nt][2 * q + 1] + bias[nt], 0.f);
            const float m2 = fmaxf(acc[2 * half + 1][nt][2 * q] + bias[nt], 0.f);
            const float m3 = fmaxf(acc[2 * half + 1][nt][2 * q + 1] + bias[nt], 0.f);
            const float mx = fmaxf(fmaxf(m0, m1), fmaxf(m2, m3));
            agg[nt][0] += mx;
            if (rT) agg[nt][1] += mx;
            if (rB) agg[nt][2] += mx;
            if (cL) agg[nt][3] += mx;
            if (cR) agg[nt][4] += mx;
            if (rT && cL) agg[nt][5] += mx;
            if (rT && cR) agg[nt][6] += mx;
            if (rB && cL) agg[nt][7] += mx;
            if (rB && cR) agg[nt][8] += mx;
          }
        }
      }

#pragma unroll
      for (int nt = 0; nt < 2; ++nt)
#pragma unroll
        for (int a = 0; a < 9; ++a) {
          float v = agg[nt][a];
          v += __shfl_xor(v, 16, 64);
          v += __shfl_xor(v, 32, 64);
          agg[nt][a] = v;
        }
      if (lg == 0) {
#pragma unroll
        for (int nt = 0; nt < 2; ++nt)
#pragma unroll
          for (int a = 0; a < 9; ++a)
            sred[((w * 2 + nt) * 16 + lx) * 9 + a] = agg[nt][a];
      }
      __syncthreads();
      for (int v = tid; v < 288; v += 256) {
        const int a = v >> 5;
        const int colocal = v & 31;
        const int nt = colocal >> 4, lxx = colocal & 15;
        float s = 0.f;
#pragma unroll
        for (int ww = 0; ww < 4; ++ww) s += sred[((ww * 2 + nt) * 16 + lxx) * 9 + a];
        part_s3[(size_t)(b * 32 + ti) * 288 + v] = s;
      }
    }
  }
  batch_barrier(ctr, 32u);

  // ---------------- Phase 4: final (one block per batch) -----------------------
  if (sub != 0) return;
  {
    float* AG = (float*)smem;      // [9][64]
    float* Sp = AG + 576;          // [9][64]
    float* m2 = Sp + 576;          // 64
    float* h = m2 + 64;            // 4
    float* s2 = h + 4;             // 64
    float* route = s2 + 64;        // 3 (+1)
    float* redf = route + 4;       // [2][128]

    for (int v = tid; v < 576; v += 256) {
      const int a = v >> 6, ci = v & 63;
      const int cg = ci >> 5, colocal = ci & 31;
      float s = 0.f;
#pragma unroll
      for (int tile = 0; tile < 16; ++tile)
        s += part_s3[(size_t)(b * 32 + 2 * tile + cg) * 288 + a * 32 + colocal];
      AG[a * 64 + ci] = s;
    }
    __syncthreads();
    if (tid < 64) m2[tid] = AG[tid] * (1.0f / 1024.0f);
    __syncthreads();
    if (tid < 4) {
      float z = 0.f;
      for (int c = 0; c < 64; ++c) z += m2[c] * sw2a[c * 4 + tid];
      h[tid] = fmaxf(z, 0.f);
    }
    __syncthreads();
    if (tid < 64) {
      float z = 0.f;
#pragma unroll
      for (int j = 0; j < 4; ++j) z += h[j] * sw2b[j * 64 + tid];
      s2[tid] = sigmoidf_(z);
    }
    __syncthreads();
    if (tid < 3) {
      float z = rb3[tid];
      for (int c = 0; c < 64; ++c) z += m2[c] * s2[c] * rw3[c * 3 + tid];
      route[tid] = sigmoidf_(z);
    }
    __syncthreads();
    for (int v = tid; v < 576; v += 256) {
      const int tap = v >> 6, ci = v & 63;
      const int ky = tap / 3, kx = tap - 3 * ky;
      const float T = AG[ci];
      const float A = (ky == 0) ? AG[2 * 64 + ci] : ((ky == 2) ? AG[1 * 64 + ci] : 0.f);
      const float B = (kx == 0) ? AG[4 * 64 + ci] : ((kx == 2) ? AG[3 * 64 + ci] : 0.f);
      float AB = 0.f;
      if (ky == 0 && kx == 0) AB = AG[8 * 64 + ci];
      else if (ky == 0 && kx == 2) AB = AG[7 * 64 + ci];
      else if (ky == 2 && kx == 0) AB = AG[6 * 64 + ci];
      else if (ky == 2 && kx == 2) AB = AG[5 * 64 + ci];
      Sp[tap * 64 + ci] = (T - A - B + AB) * s2[ci];
    }
    __syncthreads();

    const int co = tid & 127;
    const int half = tid >> 7;
    const int tap_lo = half ? 5 : 0;
    const int tap_hi = half ? 9 : 5;
    float acc = 0.f;
#pragma unroll
    for (int e = 0; e < 3; ++e) {
      float m = 0.f;
      for (int tap = tap_lo; tap < tap_hi; ++tap) {
        const float* E = experts3 + ((size_t)(e * 9 + tap) * 64) * 128 + co;
#pragma unroll 16
        for (int ci = 0; ci < 64; ++ci) m = fmaf(E[(size_t)ci * 128], Sp[tap * 64 + ci], m);
      }
      acc += route[e] * m;
    }
    redf[half * 128 + co] = acc;
    __syncthreads();
    if (tid < 128) {
      const float total = redf[tid] + redf[128 + tid];
      const float inv = g3[tid] * rsqrtf(va3[tid] + EPSBN);
      out[(size_t)b * 128 + tid] = total * (1.0f / 1024.0f) * inv + (be3[tid] - mu3[tid] * inv);
    }
  }
}

extern "C" void kernel_launch(void* const* d_in, const int* in_sizes, int n_in,
                              void* d_out, int out_size, void* d_ws, size_t ws_size,
                              hipStream_t stream) {
  const float* x        = (const float*)d_in[0];
  const float* experts1 = (const float*)d_in[1];
  const float* rw1      = (const float*)d_in[2];
  const float* rb1      = (const float*)d_in[3];
  const float* g1  = (const float*)d_in[4];
  const float* be1 = (const float*)d_in[5];
  const float* mu1 = (const float*)d_in[6];
  const float* va1 = (const float*)d_in[7];
  const float* sw1a = (const float*)d_in[8];
  const float* sw1b = (const float*)d_in[9];
  const float* experts2 = (const float*)d_in[10];
  const float* rw2 = (const float*)d_in[11];
  const float* rb2 = (const float*)d_in[12];
  const float* g2  = (const float*)d_in[13];
  const float* be2 = (const float*)d_in[14];
  const float* mu2 = (const float*)d_in[15];
  const float* va2 = (const float*)d_in[16];
  const float* sw2a = (const float*)d_in[17];
  const float* sw2b = (const float*)d_in[18];
  const float* experts3 = (const float*)d_in[19];
  const float* rw3 = (const float*)d_in[20];
  const float* rb3 = (const float*)d_in[21];
  const float* g3  = (const float*)d_in[22];
  const float* be3 = (const float*)d_in[23];
  const float* mu3 = (const float*)d_in[24];
  const float* va3 = (const float*)d_in[25];
  float* out = (float*)d_out;
  float* ws = (float*)d_ws;

  // workspace layout (float offsets, all 16B-aligned):
  float* meanx_part = ws;                           // 3072   [512][6]
  float* part_m1    = ws + 3072;                    // 16384  [512][32]
  ushort_t* k2pb    = (ushort_t*)(ws + 19456);      // 1,179,648 shorts = 589,824 fl
  float* part_s3    = ws + 609280;                  // 589,824  [2048][288]
  ushort_t* p1b     = (ushort_t*)(ws + 1199104);    // 8,388,608 shorts = 4,194,304 fl
  unsigned* bctr    = (unsigned*)(ws + 5393408);    // 64 uints
  // end: ~21.6 MB

  hipMemsetAsync(bctr, 0, 64 * sizeof(unsigned), stream);

  void* args[] = {
    (void*)&x, (void*)&experts1, (void*)&rw1, (void*)&rb1,
    (void*)&g1, (void*)&be1, (void*)&mu1, (void*)&va1,
    (void*)&sw1a, (void*)&sw1b, (void*)&experts2,
    (void*)&rw2, (void*)&rb2, (void*)&g2, (void*)&be2,
    (void*)&mu2, (void*)&va2, (void*)&sw2a, (void*)&sw2b,
    (void*)&experts3, (void*)&rw3, (void*)&rb3, (void*)&g3,
    (void*)&be3, (void*)&mu3, (void*)&va3, (void*)&out,
    (void*)&meanx_part, (void*)&part_m1, (void*)&k2pb,
    (void*)&part_s3, (void*)&p1b, (void*)&bctr
  };
  hipLaunchCooperativeKernel((const void*)k_fused, dim3(512), dim3(256), args, 0, stream);
}

// Round 7
// 214.746 us; speedup vs baseline: 1.9047x; 1.9047x over previous
//
#include <hip/hip_runtime.h>

#define EPSBN 1e-3f

typedef unsigned short ushort_t;
typedef __attribute__((ext_vector_type(8))) short bf8;   // 8 bf16 = 4 VGPRs
typedef __attribute__((ext_vector_type(4))) float f4;

__device__ __forceinline__ float sigmoidf_(float z) {
  return 1.0f / (1.0f + expf(-z));
}

__device__ __forceinline__ ushort_t f2bf(float x) {  // RTNE
  union { float f; unsigned u; } v; v.f = x;
  unsigned r = (v.u + 0x7fffu + ((v.u >> 16) & 1u)) >> 16;
  return (ushort_t)r;
}

// ---------------- K: partial channel sums of x + zero S_agg/done ---------------
__global__ void k_mean_x(const float* __restrict__ x, float* __restrict__ part,
                         float* __restrict__ S_agg, unsigned* __restrict__ done) {
  const int b = blockIdx.x >> 2;
  const int q = blockIdx.x & 3;
  const int tid = threadIdx.x;
  // zero this batch's S_agg slice (576 floats split across 4 blocks) + done ctr
  if (tid < 144) S_agg[(size_t)b * 576 + q * 144 + tid] = 0.0f;
  if (q == 0 && tid == 0) done[b] = 0u;

  float acc[6] = {0.f, 0.f, 0.f, 0.f, 0.f, 0.f};
  const float* xb = x + (size_t)b * 98304 + (size_t)q * 24576;
  for (int p = 0; p < 4; ++p) {
    const float* base = xb + (size_t)p * 6144 + (size_t)tid * 24;
#pragma unroll
    for (int k = 0; k < 6; ++k) {
      const float4 v = *(const float4*)(base + k * 4);
      acc[(4 * k + 0) % 6] += v.x;
      acc[(4 * k + 1) % 6] += v.y;
      acc[(4 * k + 2) % 6] += v.z;
      acc[(4 * k + 3) % 6] += v.w;
    }
  }
#pragma unroll
  for (int c = 0; c < 6; ++c)
    for (int off = 32; off > 0; off >>= 1) acc[c] += __shfl_down(acc[c], off, 64);
  __shared__ float red[4][6];
  const int lane = tid & 63, w = tid >> 6;
  if (lane == 0) {
#pragma unroll
    for (int c = 0; c < 6; ++c) red[w][c] = acc[c];
  }
  __syncthreads();
  if (tid < 6) {
    part[blockIdx.x * 6 + tid] = red[0][tid] + red[1][tid] + red[2][tid] + red[3][tid];
  }
}

// ------------- K: conv1 (fused route1/buildk1) MFMA + BN + relu + pool + mean1 -
// grid: 64 b x 4 row-tiles x 2 col-tiles = 512 blocks.
__global__ __launch_bounds__(256)
void k_conv1(const float* __restrict__ x, const float* __restrict__ meanx_part,
             const float* __restrict__ experts1,
             const float* __restrict__ rw, const float* __restrict__ rbias,
             const float* __restrict__ gamma, const float* __restrict__ beta,
             const float* __restrict__ bnmean, const float* __restrict__ bnvar,
             ushort_t* __restrict__ p1b, float* __restrict__ part_m1) {
  const int bid = blockIdx.x;
  const int b = bid >> 3;
  const int tyi = (bid >> 1) & 3;
  const int txi = bid & 1;
  __shared__ __align__(16) ushort_t patch[34 * 68 * 8];  // 36,992 B
  __shared__ float route_s[3];
  __shared__ float mred[4][32];
  const int tid = threadIdx.x;
  const float* xb = x + (size_t)b * (128 * 128 * 6);

  if (tid < 3) {
    float z = rbias[tid];
    for (int c = 0; c < 6; ++c) {
      const float s = meanx_part[(b * 4 + 0) * 6 + c] + meanx_part[(b * 4 + 1) * 6 + c] +
                      meanx_part[(b * 4 + 2) * 6 + c] + meanx_part[(b * 4 + 3) * 6 + c];
      z += (s * (1.0f / 16384.0f)) * rw[c * 3 + tid];
    }
    route_s[tid] = sigmoidf_(z);
  }

  for (int v = tid; v < 34 * 68; v += 256) {
    const int ry = v / 68, p = v - ry * 68;
    const int gy = tyi * 32 - 1 + ry, gx = txi * 64 - 1 + p;
    uint4 u = make_uint4(0u, 0u, 0u, 0u);
    if (((unsigned)gy < 128u) && ((unsigned)gx < 128u)) {
      const float* s = xb + ((size_t)(gy * 128 + gx)) * 6;
      const float2 a0 = *(const float2*)s;
      const float2 a1 = *(const float2*)(s + 2);
      const float2 a2 = *(const float2*)(s + 4);
      u.x = (unsigned)f2bf(a0.x) | ((unsigned)f2bf(a0.y) << 16);
      u.y = (unsigned)f2bf(a1.x) | ((unsigned)f2bf(a1.y) << 16);
      u.z = (unsigned)f2bf(a2.x) | ((unsigned)f2bf(a2.y) << 16);
      u.w = 0u;
    }
    *(uint4*)(patch + (size_t)v * 8) = u;
  }
  __syncthreads();

  const int w = tid >> 6;
  const int lane = tid & 63;
  const int lx = lane & 15, lg = lane >> 4;

  const float r0 = route_s[0], r1 = route_s[1], r2 = route_s[2];
  const int co0 = lx, co1 = 16 + lx;
  const float inv0 = gamma[co0] * rsqrtf(bnvar[co0] + EPSBN);
  const float bias0 = beta[co0] - bnmean[co0] * inv0;
  const float inv1 = gamma[co1] * rsqrtf(bnvar[co1] + EPSBN);
  const float bias1 = beta[co1] - bnmean[co1] * inv1;

  bf8 Bf[3][2];
#pragma unroll
  for (int ky = 0; ky < 3; ++ky) {
#pragma unroll
    for (int nt = 0; nt < 2; ++nt) {
      const int co = nt * 16 + lx;
      const float inv = nt ? inv1 : inv0;
#pragma unroll
      for (int j = 0; j < 8; ++j) {
        float val = 0.f;
        if (j < 6 && lg < 3) {
          const int idx = ((ky * 3 + lg) * 6 + j) * 32 + co;
          val = (r0 * experts1[idx] + r1 * experts1[1728 + idx] +
                 r2 * experts1[3456 + idx]) * inv;
        }
        Bf[ky][nt][j] = (short)f2bf(val);
      }
    }
  }

  float msum0 = 0.f, msum1 = 0.f;
#pragma unroll
  for (int xt = 0; xt < 4; ++xt) {
    bf8 Af[10];
#pragma unroll
    for (int r = 0; r < 10; ++r)
      Af[r] = *(const bf8*)(patch + ((size_t)(w * 8 + r) * 68 + xt * 16 + lx + lg) * 8);
#pragma unroll
    for (int rp = 0; rp < 4; ++rp) {
      const int prow = tyi * 16 + w * 4 + rp;
      f4 acc0[2], acc1[2];
#pragma unroll
      for (int nt = 0; nt < 2; ++nt) {
        acc0[nt] = (f4){0.f, 0.f, 0.f, 0.f};
        acc1[nt] = (f4){0.f, 0.f, 0.f, 0.f};
      }
#pragma unroll
      for (int ky = 0; ky < 3; ++ky) {
#pragma unroll
        for (int nt = 0; nt < 2; ++nt) {
          acc0[nt] = __builtin_amdgcn_mfma_f32_16x16x32_bf16(Af[rp * 2 + ky], Bf[ky][nt], acc0[nt], 0, 0, 0);
          acc1[nt] = __builtin_amdgcn_mfma_f32_16x16x32_bf16(Af[rp * 2 + ky + 1], Bf[ky][nt], acc1[nt], 0, 0, 0);
        }
      }
#pragma unroll
      for (int nt = 0; nt < 2; ++nt) {
        const float bias = nt ? bias1 : bias0;
        const int co = nt * 16 + lx;
#pragma unroll
        for (int q = 0; q < 2; ++q) {
          const float m0 = fmaxf(acc0[nt][2 * q] + bias, 0.f);
          const float m1 = fmaxf(acc0[nt][2 * q + 1] + bias, 0.f);
          const float m2 = fmaxf(acc1[nt][2 * q] + bias, 0.f);
          const float m3 = fmaxf(acc1[nt][2 * q + 1] + bias, 0.f);
          const float mx = fmaxf(fmaxf(m0, m1), fmaxf(m2, m3));
          if (nt) msum1 += mx; else msum0 += mx;
          const int pcol = txi * 32 + xt * 8 + lg * 2 + q;
          p1b[(((size_t)b * 64 + prow) * 64 + pcol) * 32 + co] = f2bf(mx);
        }
      }
    }
  }

  msum0 += __shfl_xor(msum0, 16, 64);
  msum0 += __shfl_xor(msum0, 32, 64);
  msum1 += __shfl_xor(msum1, 16, 64);
  msum1 += __shfl_xor(msum1, 32, 64);
  if (lg == 0) {
    mred[w][lx] = msum0;
    mred[w][16 + lx] = msum1;
  }
  __syncthreads();
  if (tid < 32) {
    part_m1[(size_t)bid * 32 + tid] =
        mred[0][tid] + mred[1][tid] + mred[2][tid] + mred[3][tid];
  }
}

// ------------- K: conv2 fused: SE1+route2 + B-build + MFMA + S3 atomics + final -
// grid: 64 b x 16 tiles x 2 cog = 2048 blocks. Last block per batch runs final.
__global__ __launch_bounds__(256)
void k_conv2f(const ushort_t* __restrict__ p1b, const float* __restrict__ part_m1,
              const float* __restrict__ experts2,
              const float* __restrict__ rw2, const float* __restrict__ rb2,
              const float* __restrict__ sw1a, const float* __restrict__ sw1b,
              const float* __restrict__ g2, const float* __restrict__ be2,
              const float* __restrict__ mu2, const float* __restrict__ va2,
              const float* __restrict__ experts3,
              const float* __restrict__ rw3, const float* __restrict__ rb3,
              const float* __restrict__ sw2a, const float* __restrict__ sw2b,
              const float* __restrict__ g3, const float* __restrict__ be3,
              const float* __restrict__ mu3, const float* __restrict__ va3,
              float* __restrict__ S_agg, unsigned* __restrict__ done,
              float* __restrict__ out) {
  const int bi = blockIdx.x;
  const int b = bi >> 5;
  const int ti = bi & 31;
  const int tile = ti >> 1, cog = ti & 1;
  const int ty = tile >> 2, tx2 = tile & 3;
  __shared__ __align__(16) unsigned char smem[53568];  // As|Bs | aux/sred
  __shared__ int is_last;
  short* As = (short*)smem;                 // 12960 shorts
  short* Bs = As + 12960;                   // 11520 shorts
  float* aux = (float*)(smem + 48960);      // 1152 floats (SE temps, then sred)
  const int tid = threadIdx.x;

  // ---- stage A from p1b (independent of SE) ----
  const ushort_t* pb = p1b + (size_t)b * 131072;
  for (int v = tid; v < 1296; v += 256) {
    const int cell = v >> 2, part = v & 3;
    const int ly = cell / 18, lx2 = cell - ly * 18;
    const int gy = ty * 16 - 1 + ly, gx = tx2 * 16 - 1 + lx2;
    uint4 d = make_uint4(0u, 0u, 0u, 0u);
    if (((unsigned)gy < 64u) && ((unsigned)gx < 64u))
      d = *(const uint4*)(pb + (((size_t)gy << 6) + gx) * 32 + part * 8);
    *(uint4*)(As + (ly * 18 + lx2) * 40 + part * 8) = d;
  }

  // ---- SE1 + route2 (redundant per block, tiny) ----
  float* m1 = aux;          // 32
  float* h = aux + 32;      // 2 (+2 pad)
  float* s1 = aux + 36;     // 32
  float* route = aux + 68;  // 3
  if (tid < 32) {
    float s = 0.f;
#pragma unroll
    for (int k = 0; k < 8; ++k) s += part_m1[(size_t)(b * 8 + k) * 32 + tid];
    m1[tid] = s * (1.0f / 4096.0f);
  }
  __syncthreads();
  if (tid < 2) {
    float z = 0.f;
    for (int c = 0; c < 32; ++c) z += m1[c] * sw1a[c * 2 + tid];
    h[tid] = fmaxf(z, 0.f);
  }
  __syncthreads();
  if (tid < 32) s1[tid] = sigmoidf_(h[0] * sw1b[tid] + h[1] * sw1b[32 + tid]);
  __syncthreads();
  if (tid < 3) {
    float z = rb2[tid];
    for (int c = 0; c < 32; ++c) z += m1[c] * s1[c] * rw2[c * 3 + tid];
    route[tid] = sigmoidf_(z);
  }
  __syncthreads();

  // ---- build B tile bf16 in LDS from experts2 (cog half only) ----
  const float r0 = route[0], r1 = route[1], r2 = route[2];
  const int n_l = tid & 31;  // local co within cog half (constant across j)
  const int co_g = cog * 32 + n_l;
  const float inv2c = g2[co_g] * rsqrtf(va2[co_g] + EPSBN);
  for (int j = 0; j < 36; ++j) {
    const int idx = j * 256 + tid;       // (tap*32+ci)*32 + n
    const int ci = (idx >> 5) & 31;
    const int tap = idx >> 10;
    const int t = (tap * 32 + ci) * 64 + co_g;
    const float v = r0 * experts2[t] + r1 * experts2[18432 + t] + r2 * experts2[36864 + t];
    Bs[(tap * 32 + n_l) * 40 + ci] = (short)f2bf(v * s1[ci] * inv2c);
  }
  __syncthreads();

  const int w = tid >> 6;
  const int lane = tid & 63;
  const int lx = lane & 15, lg = lane >> 4;

  f4 acc[4][2];
#pragma unroll
  for (int mt = 0; mt < 4; ++mt)
#pragma unroll
    for (int nt = 0; nt < 2; ++nt)
      acc[mt][nt] = (f4){0.f, 0.f, 0.f, 0.f};

#pragma unroll
  for (int kx = 0; kx < 3; ++kx) {
    bf8 Af[6];
#pragma unroll
    for (int r = 0; r < 6; ++r)
      Af[r] = *(const bf8*)(As + ((4 * w + r) * 18 + lx + kx) * 40 + (lg << 3));
#pragma unroll
    for (int ky = 0; ky < 3; ++ky) {
      const int t = ky * 3 + kx;
      const bf8 Bf0 = *(const bf8*)(Bs + ((t << 5) + lx) * 40 + (lg << 3));
      const bf8 Bf1 = *(const bf8*)(Bs + ((t << 5) + 16 + lx) * 40 + (lg << 3));
#pragma unroll
      for (int mt = 0; mt < 4; ++mt) {
        acc[mt][0] = __builtin_amdgcn_mfma_f32_16x16x32_bf16(Af[ky + mt], Bf0, acc[mt][0], 0, 0, 0);
        acc[mt][1] = __builtin_amdgcn_mfma_f32_16x16x32_bf16(Af[ky + mt], Bf1, acc[mt][1], 0, 0, 0);
      }
    }
  }

  // ---- epilogue: BN + relu + pool + 9 boundary aggregates ----
  float inv[2], bias[2];
#pragma unroll
  for (int nt = 0; nt < 2; ++nt) {
    const int co = cog * 32 + nt * 16 + lx;
    inv[nt] = g2[co] * rsqrtf(va2[co] + EPSBN);
    bias[nt] = be2[co] - mu2[co] * inv[nt];
  }
  float agg[2][9];
#pragma unroll
  for (int nt = 0; nt < 2; ++nt)
#pragma unroll
    for (int a = 0; a < 9; ++a) agg[nt][a] = 0.f;

#pragma unroll
  for (int half = 0; half < 2; ++half) {
    const int prow = ty * 8 + 2 * w + half;
    const bool rT = (prow == 0), rB = (prow == 31);
#pragma unroll
    for (int q = 0; q < 2; ++q) {
      const int pcol = tx2 * 8 + 2 * lg + q;
      const bool cL = (pcol == 0), cR = (pcol == 31);
#pragma unroll
      for (int nt = 0; nt < 2; ++nt) {
        const float m0 = fmaxf(acc[2 * half][nt][2 * q] + bias[nt], 0.f);
        const float m1 = fmaxf(acc[2 * half][nt][2 * q + 1] + bias[nt], 0.f);
        const float m2 = fmaxf(acc[2 * half + 1][nt][2 * q] + bias[nt], 0.f);
        const float m3 = fmaxf(acc[2 * half + 1][nt][2 * q + 1] + bias[nt], 0.f);
        const float mx = fmaxf(fmaxf(m0, m1), fmaxf(m2, m3));
        agg[nt][0] += mx;
        if (rT) agg[nt][1] += mx;
        if (rB) agg[nt][2] += mx;
        if (cL) agg[nt][3] += mx;
        if (cR) agg[nt][4] += mx;
        if (rT && cL) agg[nt][5] += mx;
        if (rT && cR) agg[nt][6] += mx;
        if (rB && cL) agg[nt][7] += mx;
        if (rB && cR) agg[nt][8] += mx;
      }
    }
  }

#pragma unroll
  for (int nt = 0; nt < 2; ++nt)
#pragma unroll
    for (int a = 0; a < 9; ++a) {
      float v = agg[nt][a];
      v += __shfl_xor(v, 16, 64);
      v += __shfl_xor(v, 32, 64);
      agg[nt][a] = v;
    }
  float* sred = aux;  // reuse (SE temps dead)
  if (lg == 0) {
#pragma unroll
    for (int nt = 0; nt < 2; ++nt)
#pragma unroll
      for (int a = 0; a < 9; ++a)
        sred[((w * 2 + nt) * 16 + lx) * 9 + a] = agg[nt][a];
  }
  __syncthreads();
  for (int v = tid; v < 288; v += 256) {
    const int a = v >> 5;
    const int colocal = v & 31;
    const int nt = colocal >> 4, lxx = colocal & 15;
    float s = 0.f;
#pragma unroll
    for (int ww = 0; ww < 4; ++ww) s += sred[((ww * 2 + nt) * 16 + lxx) * 9 + a];
    atomicAdd(&S_agg[(size_t)b * 576 + a * 64 + cog * 32 + colocal], s);
  }

  // ---- last-block-finishes: only the 32nd arriving block runs the tail ----
  __syncthreads();  // implies s_waitcnt vmcnt(0): atomics drained
  if (tid == 0) {
    const unsigned old = atomicAdd(&done[b], 1u);
    is_last = (old == 31u) ? 1 : 0;
  }
  __syncthreads();
  if (!is_last) return;

  // ---- final: SE2 + route3 + expert contraction + BN3 (reuse smem) ----
  float* AG = (float*)smem;      // 576
  float* Sp = AG + 576;          // 576
  float* m2 = Sp + 576;          // 64
  float* hh = m2 + 64;           // 4
  float* s2 = hh + 4;            // 64
  float* rt = s2 + 64;           // 3 (+1)
  float* redf = rt + 4;          // 256
  for (int v = tid; v < 576; v += 256)
    AG[v] = atomicAdd(&S_agg[(size_t)b * 576 + v], 0.0f);  // coherent read
  __syncthreads();
  if (tid < 64) m2[tid] = AG[tid] * (1.0f / 1024.0f);
  __syncthreads();
  if (tid < 4) {
    float z = 0.f;
    for (int c = 0; c < 64; ++c) z += m2[c] * sw2a[c * 4 + tid];
    hh[tid] = fmaxf(z, 0.f);
  }
  __syncthreads();
  if (tid < 64) {
    float z = 0.f;
#pragma unroll
    for (int j = 0; j < 4; ++j) z += hh[j] * sw2b[j * 64 + tid];
    s2[tid] = sigmoidf_(z);
  }
  __syncthreads();
  if (tid < 3) {
    float z = rb3[tid];
    for (int c = 0; c < 64; ++c) z += m2[c] * s2[c] * rw3[c * 3 + tid];
    rt[tid] = sigmoidf_(z);
  }
  __syncthreads();
  for (int v = tid; v < 576; v += 256) {
    const int tap = v >> 6, ci = v & 63;
    const int ky = tap / 3, kx = tap - 3 * ky;
    const float T = AG[ci];
    const float A = (ky == 0) ? AG[2 * 64 + ci] : ((ky == 2) ? AG[1 * 64 + ci] : 0.f);
    const float B = (kx == 0) ? AG[4 * 64 + ci] : ((kx == 2) ? AG[3 * 64 + ci] : 0.f);
    float AB = 0.f;
    if (ky == 0 && kx == 0) AB = AG[8 * 64 + ci];
    else if (ky == 0 && kx == 2) AB = AG[7 * 64 + ci];
    else if (ky == 2 && kx == 0) AB = AG[6 * 64 + ci];
    else if (ky == 2 && kx == 2) AB = AG[5 * 64 + ci];
    Sp[tap * 64 + ci] = (T - A - B + AB) * s2[ci];
  }
  __syncthreads();

  const int co = tid & 127;
  const int hf = tid >> 7;
  const int tap_lo = hf ? 5 : 0;
  const int tap_hi = hf ? 9 : 5;
  float acc2 = 0.f;
#pragma unroll
  for (int e = 0; e < 3; ++e) {
    float m = 0.f;
    for (int tap = tap_lo; tap < tap_hi; ++tap) {
      const float* E = experts3 + ((size_t)(e * 9 + tap) * 64) * 128 + co;
#pragma unroll 16
      for (int ci = 0; ci < 64; ++ci) m = fmaf(E[(size_t)ci * 128], Sp[tap * 64 + ci], m);
    }
    acc2 += rt[e] * m;
  }
  redf[hf * 128 + co] = acc2;
  __syncthreads();
  if (tid < 128) {
    const float total = redf[tid] + redf[128 + tid];
    const float invf = g3[tid] * rsqrtf(va3[tid] + EPSBN);
    out[(size_t)b * 128 + tid] = total * (1.0f / 1024.0f) * invf + (be3[tid] - mu3[tid] * invf);
  }
}

extern "C" void kernel_launch(void* const* d_in, const int* in_sizes, int n_in,
                              void* d_out, int out_size, void* d_ws, size_t ws_size,
                              hipStream_t stream) {
  const float* x        = (const float*)d_in[0];
  const float* experts1 = (const float*)d_in[1];
  const float* rw1      = (const float*)d_in[2];
  const float* rb1      = (const float*)d_in[3];
  const float* g1  = (const float*)d_in[4];
  const float* be1 = (const float*)d_in[5];
  const float* mu1 = (const float*)d_in[6];
  const float* va1 = (const float*)d_in[7];
  const float* sw1a = (const float*)d_in[8];
  const float* sw1b = (const float*)d_in[9];
  const float* experts2 = (const float*)d_in[10];
  const float* rw2 = (const float*)d_in[11];
  const float* rb2 = (const float*)d_in[12];
  const float* g2  = (const float*)d_in[13];
  const float* be2 = (const float*)d_in[14];
  const float* mu2 = (const float*)d_in[15];
  const float* va2 = (const float*)d_in[16];
  const float* sw2a = (const float*)d_in[17];
  const float* sw2b = (const float*)d_in[18];
  const float* experts3 = (const float*)d_in[19];
  const float* rw3 = (const float*)d_in[20];
  const float* rb3 = (const float*)d_in[21];
  const float* g3  = (const float*)d_in[22];
  const float* be3 = (const float*)d_in[23];
  const float* mu3 = (const float*)d_in[24];
  const float* va3 = (const float*)d_in[25];
  float* out = (float*)d_out;
  float* ws = (float*)d_ws;

  // workspace layout (float offsets, all 16B-aligned):
  float* meanx_part = ws;                           // 1536   [256][6]
  float* part_m1    = ws + 1536;                    // 16384  [512][32]
  float* S_agg      = ws + 17920;                   // 36864  [64][576]
  unsigned* done    = (unsigned*)(ws + 54784);      // 64
  ushort_t* p1b     = (ushort_t*)(ws + 54848);      // 8,388,608 shorts
  // end: ~17 MB

  hipLaunchKernelGGL(k_mean_x, dim3(256), dim3(256), 0, stream, x, meanx_part, S_agg, done);
  hipLaunchKernelGGL(k_conv1, dim3(512), dim3(256), 0, stream,
                     x, meanx_part, experts1, rw1, rb1, g1, be1, mu1, va1, p1b, part_m1);
  hipLaunchKernelGGL(k_conv2f, dim3(2048), dim3(256), 0, stream,
                     p1b, part_m1, experts2, rw2, rb2, sw1a, sw1b, g2, be2, mu2, va2,
                     experts3, rw3, rb3, sw2a, sw2b, g3, be3, mu3, va3,
                     S_agg, done, out);
}

// Round 8
// 213.117 us; speedup vs baseline: 1.9193x; 1.0076x over previous
//
#include <hip/hip_runtime.h>

#define EPSBN 1e-3f

typedef unsigned short ushort_t;
typedef __attribute__((ext_vector_type(8))) short bf8;   // 8 bf16 = 4 VGPRs
typedef __attribute__((ext_vector_type(4))) float f4;

__device__ __forceinline__ float sigmoidf_(float z) {
  return 1.0f / (1.0f + expf(-z));
}

__device__ __forceinline__ ushort_t f2bf(float x) {  // RTNE
  union { float f; unsigned u; } v; v.f = x;
  unsigned r = (v.u + 0x7fffu + ((v.u >> 16) & 1u)) >> 16;
  return (ushort_t)r;
}

// ---------------- K: partial channel sums of x + zero S_agg/done ---------------
__global__ void k_mean_x(const float* __restrict__ x, float* __restrict__ part,
                         float* __restrict__ S_agg, unsigned* __restrict__ done) {
  const int b = blockIdx.x >> 2;
  const int q = blockIdx.x & 3;
  const int tid = threadIdx.x;
  if (tid < 144) S_agg[(size_t)b * 576 + q * 144 + tid] = 0.0f;
  if (q == 0 && tid == 0) done[b] = 0u;

  float acc[6] = {0.f, 0.f, 0.f, 0.f, 0.f, 0.f};
  const float* xb = x + (size_t)b * 98304 + (size_t)q * 24576;
  for (int p = 0; p < 4; ++p) {
    const float* base = xb + (size_t)p * 6144 + (size_t)tid * 24;
#pragma unroll
    for (int k = 0; k < 6; ++k) {
      const float4 v = *(const float4*)(base + k * 4);
      acc[(4 * k + 0) % 6] += v.x;
      acc[(4 * k + 1) % 6] += v.y;
      acc[(4 * k + 2) % 6] += v.z;
      acc[(4 * k + 3) % 6] += v.w;
    }
  }
#pragma unroll
  for (int c = 0; c < 6; ++c)
    for (int off = 32; off > 0; off >>= 1) acc[c] += __shfl_down(acc[c], off, 64);
  __shared__ float red[4][6];
  const int lane = tid & 63, w = tid >> 6;
  if (lane == 0) {
#pragma unroll
    for (int c = 0; c < 6; ++c) red[w][c] = acc[c];
  }
  __syncthreads();
  if (tid < 6) {
    part[blockIdx.x * 6 + tid] = red[0][tid] + red[1][tid] + red[2][tid] + red[3][tid];
  }
}

// ------------- K: conv1 (fused route1/buildk1) MFMA + BN + relu + pool + mean1 -
__global__ __launch_bounds__(256)
void k_conv1(const float* __restrict__ x, const float* __restrict__ meanx_part,
             const float* __restrict__ experts1,
             const float* __restrict__ rw, const float* __restrict__ rbias,
             const float* __restrict__ gamma, const float* __restrict__ beta,
             const float* __restrict__ bnmean, const float* __restrict__ bnvar,
             ushort_t* __restrict__ p1b, float* __restrict__ part_m1) {
  const int bid = blockIdx.x;
  const int b = bid >> 3;
  const int tyi = (bid >> 1) & 3;
  const int txi = bid & 1;
  __shared__ __align__(16) ushort_t patch[34 * 68 * 8];  // 36,992 B
  __shared__ float route_s[3];
  __shared__ float mred[4][32];
  const int tid = threadIdx.x;
  const float* xb = x + (size_t)b * (128 * 128 * 6);

  if (tid < 3) {
    float z = rbias[tid];
    for (int c = 0; c < 6; ++c) {
      const float s = meanx_part[(b * 4 + 0) * 6 + c] + meanx_part[(b * 4 + 1) * 6 + c] +
                      meanx_part[(b * 4 + 2) * 6 + c] + meanx_part[(b * 4 + 3) * 6 + c];
      z += (s * (1.0f / 16384.0f)) * rw[c * 3 + tid];
    }
    route_s[tid] = sigmoidf_(z);
  }

  for (int v = tid; v < 34 * 68; v += 256) {
    const int ry = v / 68, p = v - ry * 68;
    const int gy = tyi * 32 - 1 + ry, gx = txi * 64 - 1 + p;
    uint4 u = make_uint4(0u, 0u, 0u, 0u);
    if (((unsigned)gy < 128u) && ((unsigned)gx < 128u)) {
      const float* s = xb + ((size_t)(gy * 128 + gx)) * 6;
      const float2 a0 = *(const float2*)s;
      const float2 a1 = *(const float2*)(s + 2);
      const float2 a2 = *(const float2*)(s + 4);
      u.x = (unsigned)f2bf(a0.x) | ((unsigned)f2bf(a0.y) << 16);
      u.y = (unsigned)f2bf(a1.x) | ((unsigned)f2bf(a1.y) << 16);
      u.z = (unsigned)f2bf(a2.x) | ((unsigned)f2bf(a2.y) << 16);
      u.w = 0u;
    }
    *(uint4*)(patch + (size_t)v * 8) = u;
  }
  __syncthreads();

  const int w = tid >> 6;
  const int lane = tid & 63;
  const int lx = lane & 15, lg = lane >> 4;

  const float r0 = route_s[0], r1 = route_s[1], r2 = route_s[2];
  const int co0 = lx, co1 = 16 + lx;
  const float inv0 = gamma[co0] * rsqrtf(bnvar[co0] + EPSBN);
  const float bias0 = beta[co0] - bnmean[co0] * inv0;
  const float inv1 = gamma[co1] * rsqrtf(bnvar[co1] + EPSBN);
  const float bias1 = beta[co1] - bnmean[co1] * inv1;

  bf8 Bf[3][2];
#pragma unroll
  for (int ky = 0; ky < 3; ++ky) {
#pragma unroll
    for (int nt = 0; nt < 2; ++nt) {
      const int co = nt * 16 + lx;
      const float inv = nt ? inv1 : inv0;
#pragma unroll
      for (int j = 0; j < 8; ++j) {
        float val = 0.f;
        if (j < 6 && lg < 3) {
          const int idx = ((ky * 3 + lg) * 6 + j) * 32 + co;
          val = (r0 * experts1[idx] + r1 * experts1[1728 + idx] +
                 r2 * experts1[3456 + idx]) * inv;
        }
        Bf[ky][nt][j] = (short)f2bf(val);
      }
    }
  }

  float msum0 = 0.f, msum1 = 0.f;
#pragma unroll
  for (int xt = 0; xt < 4; ++xt) {
    bf8 Af[10];
#pragma unroll
    for (int r = 0; r < 10; ++r)
      Af[r] = *(const bf8*)(patch + ((size_t)(w * 8 + r) * 68 + xt * 16 + lx + lg) * 8);
#pragma unroll
    for (int rp = 0; rp < 4; ++rp) {
      const int prow = tyi * 16 + w * 4 + rp;
      f4 acc0[2], acc1[2];
#pragma unroll
      for (int nt = 0; nt < 2; ++nt) {
        acc0[nt] = (f4){0.f, 0.f, 0.f, 0.f};
        acc1[nt] = (f4){0.f, 0.f, 0.f, 0.f};
      }
#pragma unroll
      for (int ky = 0; ky < 3; ++ky) {
#pragma unroll
        for (int nt = 0; nt < 2; ++nt) {
          acc0[nt] = __builtin_amdgcn_mfma_f32_16x16x32_bf16(Af[rp * 2 + ky], Bf[ky][nt], acc0[nt], 0, 0, 0);
          acc1[nt] = __builtin_amdgcn_mfma_f32_16x16x32_bf16(Af[rp * 2 + ky + 1], Bf[ky][nt], acc1[nt], 0, 0, 0);
        }
      }
#pragma unroll
      for (int nt = 0; nt < 2; ++nt) {
        const float bias = nt ? bias1 : bias0;
        const int co = nt * 16 + lx;
#pragma unroll
        for (int q = 0; q < 2; ++q) {
          const float m0 = fmaxf(acc0[nt][2 * q] + bias, 0.f);
          const float m1 = fmaxf(acc0[nt][2 * q + 1] + bias, 0.f);
          const float m2 = fmaxf(acc1[nt][2 * q] + bias, 0.f);
          const float m3 = fmaxf(acc1[nt][2 * q + 1] + bias, 0.f);
          const float mx = fmaxf(fmaxf(m0, m1), fmaxf(m2, m3));
          if (nt) msum1 += mx; else msum0 += mx;
          const int pcol = txi * 32 + xt * 8 + lg * 2 + q;
          p1b[(((size_t)b * 64 + prow) * 64 + pcol) * 32 + co] = f2bf(mx);
        }
      }
    }
  }

  msum0 += __shfl_xor(msum0, 16, 64);
  msum0 += __shfl_xor(msum0, 32, 64);
  msum1 += __shfl_xor(msum1, 16, 64);
  msum1 += __shfl_xor(msum1, 32, 64);
  if (lg == 0) {
    mred[w][lx] = msum0;
    mred[w][16 + lx] = msum1;
  }
  __syncthreads();
  if (tid < 32) {
    part_m1[(size_t)bid * 32 + tid] =
        mred[0][tid] + mred[1][tid] + mred[2][tid] + mred[3][tid];
  }
}

// ------------- K: SE1 + route2 + build k2' bf16 [b][tap][co][ci] (192 blocks) --
__global__ void k_buildk2(const float* __restrict__ part_m1,
                          const float* __restrict__ experts2,
                          const float* __restrict__ rw, const float* __restrict__ rb,
                          const float* __restrict__ w1, const float* __restrict__ w2,
                          const float* __restrict__ gamma, const float* __restrict__ var,
                          ushort_t* __restrict__ k2pb) {
  const int b = blockIdx.x / 3;
  const int seg = blockIdx.x - b * 3;
  const int tid = threadIdx.x;
  __shared__ float m1[32], h[2], s1[32], route[3];
  if (tid < 32) {
    float s = 0.f;
#pragma unroll
    for (int k = 0; k < 8; ++k) s += part_m1[(size_t)(b * 8 + k) * 32 + tid];
    m1[tid] = s * (1.0f / 4096.0f);
  }
  __syncthreads();
  if (tid < 2) {
    float z = 0.f;
    for (int c = 0; c < 32; ++c) z += m1[c] * w1[c * 2 + tid];
    h[tid] = fmaxf(z, 0.f);
  }
  __syncthreads();
  if (tid < 32) s1[tid] = sigmoidf_(h[0] * w2[tid] + h[1] * w2[32 + tid]);
  __syncthreads();
  if (tid < 3) {
    float z = rb[tid];
    for (int c = 0; c < 32; ++c) z += m1[c] * s1[c] * rw[c * 3 + tid];
    route[tid] = sigmoidf_(z);
  }
  __syncthreads();
  const float r0 = route[0], r1 = route[1], r2 = route[2];
  const int t_lo = seg * 6144, t_hi = t_lo + 6144;
  for (int t = t_lo + tid; t < t_hi; t += 256) {
    const int co = t & 63;
    const int ci = (t >> 6) & 31;
    const int tap = t >> 11;
    const float inv = gamma[co] * rsqrtf(var[co] + EPSBN);
    const float v = r0 * experts2[t] + r1 * experts2[18432 + t] + r2 * experts2[2 * 18432 + t];
    k2pb[(size_t)b * 18432 + ((size_t)tap * 64 + co) * 32 + ci] = f2bf(v * s1[ci] * inv);
  }
}

// ------------- K: conv2 MFMA + BN + relu + pool + atomic S3 + last-block final -
// grid: 64 b x 16 tiles x 2 cog = 2048 blocks.
__global__ __launch_bounds__(256)
void k_conv2f(const ushort_t* __restrict__ p1b, const ushort_t* __restrict__ k2pb,
              const float* __restrict__ g2, const float* __restrict__ be2,
              const float* __restrict__ mu2, const float* __restrict__ va2,
              const float* __restrict__ experts3,
              const float* __restrict__ rw3, const float* __restrict__ rb3,
              const float* __restrict__ sw2a, const float* __restrict__ sw2b,
              const float* __restrict__ g3, const float* __restrict__ be3,
              const float* __restrict__ mu3, const float* __restrict__ va3,
              float* __restrict__ S_agg, unsigned* __restrict__ done,
              float* __restrict__ out) {
  const int bi = blockIdx.x;
  const int b = bi >> 5;
  const int tile = (bi >> 1) & 15;
  const int cog = bi & 1;
  const int ty = tile >> 2, tx2 = tile & 3;
  __shared__ __align__(16) short smem[24480];  // As 12960 + Bs 11520 shorts = 48,960 B
  __shared__ int is_last;
  short* As = smem;
  short* Bs = smem + 12960;
  const int tid = threadIdx.x;

  const ushort_t* pb = p1b + (size_t)b * 131072;
  for (int v = tid; v < 1296; v += 256) {
    const int cell = v >> 2, part = v & 3;
    const int ly = cell / 18, lx2 = cell - ly * 18;
    const int gy = ty * 16 - 1 + ly, gx = tx2 * 16 - 1 + lx2;
    uint4 d = make_uint4(0u, 0u, 0u, 0u);
    if (((unsigned)gy < 64u) && ((unsigned)gx < 64u))
      d = *(const uint4*)(pb + (((size_t)gy << 6) + gx) * 32 + part * 8);
    *(uint4*)(As + (ly * 18 + lx2) * 40 + part * 8) = d;
  }
  for (int v = tid; v < 1152; v += 256) {
    const int r = v >> 2, part = v & 3;
    const int t = r >> 5, n = r & 31;
    const uint4 d = *(const uint4*)(k2pb + (size_t)b * 18432 +
                                    ((size_t)(t * 64 + cog * 32 + n)) * 32 + part * 8);
    *(uint4*)(Bs + r * 40 + part * 8) = d;
  }
  __syncthreads();

  const int w = tid >> 6;
  const int lane = tid & 63;
  const int lx = lane & 15, lg = lane >> 4;

  f4 acc[4][2];
#pragma unroll
  for (int mt = 0; mt < 4; ++mt)
#pragma unroll
    for (int nt = 0; nt < 2; ++nt)
      acc[mt][nt] = (f4){0.f, 0.f, 0.f, 0.f};

#pragma unroll
  for (int kx = 0; kx < 3; ++kx) {
    bf8 Af[6];
#pragma unroll
    for (int r = 0; r < 6; ++r)
      Af[r] = *(const bf8*)(As + ((4 * w + r) * 18 + lx + kx) * 40 + (lg << 3));
#pragma unroll
    for (int ky = 0; ky < 3; ++ky) {
      const int t = ky * 3 + kx;
      const bf8 Bf0 = *(const bf8*)(Bs + ((t << 5) + lx) * 40 + (lg << 3));
      const bf8 Bf1 = *(const bf8*)(Bs + ((t << 5) + 16 + lx) * 40 + (lg << 3));
#pragma unroll
      for (int mt = 0; mt < 4; ++mt) {
        acc[mt][0] = __builtin_amdgcn_mfma_f32_16x16x32_bf16(Af[ky + mt], Bf0, acc[mt][0], 0, 0, 0);
        acc[mt][1] = __builtin_amdgcn_mfma_f32_16x16x32_bf16(Af[ky + mt], Bf1, acc[mt][1], 0, 0, 0);
      }
    }
  }

  float inv[2], bias[2];
#pragma unroll
  for (int nt = 0; nt < 2; ++nt) {
    const int co = cog * 32 + nt * 16 + lx;
    inv[nt] = g2[co] * rsqrtf(va2[co] + EPSBN);
    bias[nt] = be2[co] - mu2[co] * inv[nt];
  }
  float agg[2][9];
#pragma unroll
  for (int nt = 0; nt < 2; ++nt)
#pragma unroll
    for (int a = 0; a < 9; ++a) agg[nt][a] = 0.f;

#pragma unroll
  for (int half = 0; half < 2; ++half) {
    const int prow = ty * 8 + 2 * w + half;
    const bool rT = (prow == 0), rB = (prow == 31);
#pragma unroll
    for (int q = 0; q < 2; ++q) {
      const int pcol = tx2 * 8 + 2 * lg + q;
      const bool cL = (pcol == 0), cR = (pcol == 31);
#pragma unroll
      for (int nt = 0; nt < 2; ++nt) {
        const float m0 = fmaxf(acc[2 * half][nt][2 * q] + bias[nt], 0.f);
        const float m1 = fmaxf(acc[2 * half][nt][2 * q + 1] + bias[nt], 0.f);
        const float m2 = fmaxf(acc[2 * half + 1][nt][2 * q] + bias[nt], 0.f);
        const float m3 = fmaxf(acc[2 * half + 1][nt][2 * q + 1] + bias[nt], 0.f);
        const float mx = fmaxf(fmaxf(m0, m1), fmaxf(m2, m3));
        agg[nt][0] += mx;
        if (rT) agg[nt][1] += mx;
        if (rB) agg[nt][2] += mx;
        if (cL) agg[nt][3] += mx;
        if (cR) agg[nt][4] += mx;
        if (rT && cL) agg[nt][5] += mx;
        if (rT && cR) agg[nt][6] += mx;
        if (rB && cL) agg[nt][7] += mx;
        if (rB && cR) agg[nt][8] += mx;
      }
    }
  }

#pragma unroll
  for (int nt = 0; nt < 2; ++nt)
#pragma unroll
    for (int a = 0; a < 9; ++a) {
      float v = agg[nt][a];
      v += __shfl_xor(v, 16, 64);
      v += __shfl_xor(v, 32, 64);
      agg[nt][a] = v;
    }
  __syncthreads();  // done with As/Bs; reuse for sred
  float* sred = (float*)smem;  // [4][2][16][9]
  if (lg == 0) {
#pragma unroll
    for (int nt = 0; nt < 2; ++nt)
#pragma unroll
      for (int a = 0; a < 9; ++a)
        sred[((w * 2 + nt) * 16 + lx) * 9 + a] = agg[nt][a];
  }
  __syncthreads();
  for (int v = tid; v < 288; v += 256) {
    const int a = v >> 5;
    const int colocal = v & 31;
    const int nt = colocal >> 4, lxx = colocal & 15;
    float s = 0.f;
#pragma unroll
    for (int ww = 0; ww < 4; ++ww) s += sred[((ww * 2 + nt) * 16 + lxx) * 9 + a];
    atomicAdd(&S_agg[(size_t)b * 576 + a * 64 + cog * 32 + colocal], s);
  }

  // ---- last-block-finishes tail ----
  __syncthreads();  // drains vmcnt: this block's atomics complete
  if (tid == 0) {
    const unsigned old = atomicAdd(&done[b], 1u);
    is_last = (old == 31u) ? 1 : 0;
  }
  __syncthreads();
  if (!is_last) return;

  float* AG = (float*)smem;      // 576
  float* Sp = AG + 576;          // 576
  float* m2 = Sp + 576;          // 64
  float* hh = m2 + 64;           // 4
  float* s2 = hh + 4;            // 64
  float* rt = s2 + 64;           // 3 (+1)
  float* redf = rt + 4;          // 256
  for (int v = tid; v < 576; v += 256)
    AG[v] = atomicAdd(&S_agg[(size_t)b * 576 + v], 0.0f);  // coherent read
  __syncthreads();
  if (tid < 64) m2[tid] = AG[tid] * (1.0f / 1024.0f);
  __syncthreads();
  if (tid < 4) {
    float z = 0.f;
    for (int c = 0; c < 64; ++c) z += m2[c] * sw2a[c * 4 + tid];
    hh[tid] = fmaxf(z, 0.f);
  }
  __syncthreads();
  if (tid < 64) {
    float z = 0.f;
#pragma unroll
    for (int j = 0; j < 4; ++j) z += hh[j] * sw2b[j * 64 + tid];
    s2[tid] = sigmoidf_(z);
  }
  __syncthreads();
  if (tid < 3) {
    float z = rb3[tid];
    for (int c = 0; c < 64; ++c) z += m2[c] * s2[c] * rw3[c * 3 + tid];
    rt[tid] = sigmoidf_(z);
  }
  __syncthreads();
  for (int v = tid; v < 576; v += 256) {
    const int tap = v >> 6, ci = v & 63;
    const int ky = tap / 3, kx = tap - 3 * ky;
    const float T = AG[ci];
    const float A = (ky == 0) ? AG[2 * 64 + ci] : ((ky == 2) ? AG[1 * 64 + ci] : 0.f);
    const float B = (kx == 0) ? AG[4 * 64 + ci] : ((kx == 2) ? AG[3 * 64 + ci] : 0.f);
    float AB = 0.f;
    if (ky == 0 && kx == 0) AB = AG[8 * 64 + ci];
    else if (ky == 0 && kx == 2) AB = AG[7 * 64 + ci];
    else if (ky == 2 && kx == 0) AB = AG[6 * 64 + ci];
    else if (ky == 2 && kx == 2) AB = AG[5 * 64 + ci];
    Sp[tap * 64 + ci] = (T - A - B + AB) * s2[ci];
  }
  __syncthreads();

  const int co = tid & 127;
  const int hf = tid >> 7;
  const int tap_lo = hf ? 5 : 0;
  const int tap_hi = hf ? 9 : 5;
  float acc2 = 0.f;
#pragma unroll
  for (int e = 0; e < 3; ++e) {
    float m = 0.f;
    for (int tap = tap_lo; tap < tap_hi; ++tap) {
      const float* E = experts3 + ((size_t)(e * 9 + tap) * 64) * 128 + co;
#pragma unroll 16
      for (int ci = 0; ci < 64; ++ci) m = fmaf(E[(size_t)ci * 128], Sp[tap * 64 + ci], m);
    }
    acc2 += rt[e] * m;
  }
  redf[hf * 128 + co] = acc2;
  __syncthreads();
  if (tid < 128) {
    const float total = redf[tid] + redf[128 + tid];
    const float invf = g3[tid] * rsqrtf(va3[tid] + EPSBN);
    out[(size_t)b * 128 + tid] = total * (1.0f / 1024.0f) * invf + (be3[tid] - mu3[tid] * invf);
  }
}

extern "C" void kernel_launch(void* const* d_in, const int* in_sizes, int n_in,
                              void* d_out, int out_size, void* d_ws, size_t ws_size,
                              hipStream_t stream) {
  const float* x        = (const float*)d_in[0];
  const float* experts1 = (const float*)d_in[1];
  const float* rw1      = (const float*)d_in[2];
  const float* rb1      = (const float*)d_in[3];
  const float* g1  = (const float*)d_in[4];
  const float* be1 = (const float*)d_in[5];
  const float* mu1 = (const float*)d_in[6];
  const float* va1 = (const float*)d_in[7];
  const float* sw1a = (const float*)d_in[8];
  const float* sw1b = (const float*)d_in[9];
  const float* experts2 = (const float*)d_in[10];
  const float* rw2 = (const float*)d_in[11];
  const float* rb2 = (const float*)d_in[12];
  const float* g2  = (const float*)d_in[13];
  const float* be2 = (const float*)d_in[14];
  const float* mu2 = (const float*)d_in[15];
  const float* va2 = (const float*)d_in[16];
  const float* sw2a = (const float*)d_in[17];
  const float* sw2b = (const float*)d_in[18];
  const float* experts3 = (const float*)d_in[19];
  const float* rw3 = (const float*)d_in[20];
  const float* rb3 = (const float*)d_in[21];
  const float* g3  = (const float*)d_in[22];
  const float* be3 = (const float*)d_in[23];
  const float* mu3 = (const float*)d_in[24];
  const float* va3 = (const float*)d_in[25];
  float* out = (float*)d_out;
  float* ws = (float*)d_ws;

  // workspace layout (float offsets, all 16B-aligned):
  float* meanx_part = ws;                           // 1536   [256][6]
  float* part_m1    = ws + 1536;                    // 16384  [512][32]
  float* S_agg      = ws + 17920;                   // 36864  [64][576]
  unsigned* done    = (unsigned*)(ws + 54784);      // 64 (+pad to 64 fl)
  ushort_t* k2pb    = (ushort_t*)(ws + 54848);      // 1,179,648 shorts = 589,824 fl
  ushort_t* p1b     = (ushort_t*)(ws + 644672);     // 8,388,608 shorts = 4,194,304 fl
  // end: 4,838,976 floats = 19.4 MB

  hipLaunchKernelGGL(k_mean_x, dim3(256), dim3(256), 0, stream, x, meanx_part, S_agg, done);
  hipLaunchKernelGGL(k_conv1, dim3(512), dim3(256), 0, stream,
                     x, meanx_part, experts1, rw1, rb1, g1, be1, mu1, va1, p1b, part_m1);
  hipLaunchKernelGGL(k_buildk2, dim3(192), dim3(256), 0, stream,
                     part_m1, experts2, rw2, rb2, sw1a, sw1b, g2, va2, k2pb);
  hipLaunchKernelGGL(k_conv2f, dim3(2048), dim3(256), 0, stream,
                     p1b, k2pb, g2, be2, mu2, va2,
                     experts3, rw3, rb3, sw2a, sw2b, g3, be3, mu3, va3,
                     S_agg, done, out);
}

// Round 9
// 188.811 us; speedup vs baseline: 2.1664x; 1.1287x over previous
//
#include <hip/hip_runtime.h>

#define EPSBN 1e-3f

typedef unsigned short ushort_t;
typedef __attribute__((ext_vector_type(8))) short bf8;   // 8 bf16 = 4 VGPRs
typedef __attribute__((ext_vector_type(4))) float f4;

__device__ __forceinline__ float sigmoidf_(float z) {
  return 1.0f / (1.0f + expf(-z));
}

__device__ __forceinline__ ushort_t f2bf(float x) {  // RTNE
  union { float f; unsigned u; } v; v.f = x;
  unsigned r = (v.u + 0x7fffu + ((v.u >> 16) & 1u)) >> 16;
  return (ushort_t)r;
}

// ---------------- K: partial channel sums of x (256 blocks = b*4+q) ------------
__global__ void k_mean_x(const float* __restrict__ x, float* __restrict__ part) {
  const int b = blockIdx.x >> 2;
  const int q = blockIdx.x & 3;
  const int tid = threadIdx.x;
  float acc[6] = {0.f, 0.f, 0.f, 0.f, 0.f, 0.f};
  const float* xb = x + (size_t)b * 98304 + (size_t)q * 24576;
  for (int p = 0; p < 4; ++p) {
    const float* base = xb + (size_t)p * 6144 + (size_t)tid * 24;
#pragma unroll
    for (int k = 0; k < 6; ++k) {
      const float4 v = *(const float4*)(base + k * 4);
      acc[(4 * k + 0) % 6] += v.x;
      acc[(4 * k + 1) % 6] += v.y;
      acc[(4 * k + 2) % 6] += v.z;
      acc[(4 * k + 3) % 6] += v.w;
    }
  }
#pragma unroll
  for (int c = 0; c < 6; ++c)
    for (int off = 32; off > 0; off >>= 1) acc[c] += __shfl_down(acc[c], off, 64);
  __shared__ float red[4][6];
  const int lane = tid & 63, w = tid >> 6;
  if (lane == 0) {
#pragma unroll
    for (int c = 0; c < 6; ++c) red[w][c] = acc[c];
  }
  __syncthreads();
  if (tid < 6) {
    part[blockIdx.x * 6 + tid] = red[0][tid] + red[1][tid] + red[2][tid] + red[3][tid];
  }
}

// ------------- K: conv1 (fused route1/buildk1) MFMA + BN + relu + pool + mean1 -
__global__ __launch_bounds__(256)
void k_conv1(const float* __restrict__ x, const float* __restrict__ meanx_part,
             const float* __restrict__ experts1,
             const float* __restrict__ rw, const float* __restrict__ rbias,
             const float* __restrict__ gamma, const float* __restrict__ beta,
             const float* __restrict__ bnmean, const float* __restrict__ bnvar,
             ushort_t* __restrict__ p1b, float* __restrict__ part_m1) {
  const int bid = blockIdx.x;
  const int b = bid >> 3;
  const int tyi = (bid >> 1) & 3;
  const int txi = bid & 1;
  __shared__ __align__(16) ushort_t patch[34 * 68 * 8];  // 36,992 B
  __shared__ float route_s[3];
  __shared__ float mred[4][32];
  const int tid = threadIdx.x;
  const float* xb = x + (size_t)b * (128 * 128 * 6);

  if (tid < 3) {
    float z = rbias[tid];
    for (int c = 0; c < 6; ++c) {
      const float s = meanx_part[(b * 4 + 0) * 6 + c] + meanx_part[(b * 4 + 1) * 6 + c] +
                      meanx_part[(b * 4 + 2) * 6 + c] + meanx_part[(b * 4 + 3) * 6 + c];
      z += (s * (1.0f / 16384.0f)) * rw[c * 3 + tid];
    }
    route_s[tid] = sigmoidf_(z);
  }

  for (int v = tid; v < 34 * 68; v += 256) {
    const int ry = v / 68, p = v - ry * 68;
    const int gy = tyi * 32 - 1 + ry, gx = txi * 64 - 1 + p;
    uint4 u = make_uint4(0u, 0u, 0u, 0u);
    if (((unsigned)gy < 128u) && ((unsigned)gx < 128u)) {
      const float* s = xb + ((size_t)(gy * 128 + gx)) * 6;
      const float2 a0 = *(const float2*)s;
      const float2 a1 = *(const float2*)(s + 2);
      const float2 a2 = *(const float2*)(s + 4);
      u.x = (unsigned)f2bf(a0.x) | ((unsigned)f2bf(a0.y) << 16);
      u.y = (unsigned)f2bf(a1.x) | ((unsigned)f2bf(a1.y) << 16);
      u.z = (unsigned)f2bf(a2.x) | ((unsigned)f2bf(a2.y) << 16);
      u.w = 0u;
    }
    *(uint4*)(patch + (size_t)v * 8) = u;
  }
  __syncthreads();

  const int w = tid >> 6;
  const int lane = tid & 63;
  const int lx = lane & 15, lg = lane >> 4;

  const float r0 = route_s[0], r1 = route_s[1], r2 = route_s[2];
  const int co0 = lx, co1 = 16 + lx;
  const float inv0 = gamma[co0] * rsqrtf(bnvar[co0] + EPSBN);
  const float bias0 = beta[co0] - bnmean[co0] * inv0;
  const float inv1 = gamma[co1] * rsqrtf(bnvar[co1] + EPSBN);
  const float bias1 = beta[co1] - bnmean[co1] * inv1;

  bf8 Bf[3][2];
#pragma unroll
  for (int ky = 0; ky < 3; ++ky) {
#pragma unroll
    for (int nt = 0; nt < 2; ++nt) {
      const int co = nt * 16 + lx;
      const float inv = nt ? inv1 : inv0;
#pragma unroll
      for (int j = 0; j < 8; ++j) {
        float val = 0.f;
        if (j < 6 && lg < 3) {
          const int idx = ((ky * 3 + lg) * 6 + j) * 32 + co;
          val = (r0 * experts1[idx] + r1 * experts1[1728 + idx] +
                 r2 * experts1[3456 + idx]) * inv;
        }
        Bf[ky][nt][j] = (short)f2bf(val);
      }
    }
  }

  float msum0 = 0.f, msum1 = 0.f;
#pragma unroll
  for (int xt = 0; xt < 4; ++xt) {
    bf8 Af[10];
#pragma unroll
    for (int r = 0; r < 10; ++r)
      Af[r] = *(const bf8*)(patch + ((size_t)(w * 8 + r) * 68 + xt * 16 + lx + lg) * 8);
#pragma unroll
    for (int rp = 0; rp < 4; ++rp) {
      const int prow = tyi * 16 + w * 4 + rp;
      f4 acc0[2], acc1[2];
#pragma unroll
      for (int nt = 0; nt < 2; ++nt) {
        acc0[nt] = (f4){0.f, 0.f, 0.f, 0.f};
        acc1[nt] = (f4){0.f, 0.f, 0.f, 0.f};
      }
#pragma unroll
      for (int ky = 0; ky < 3; ++ky) {
#pragma unroll
        for (int nt = 0; nt < 2; ++nt) {
          acc0[nt] = __builtin_amdgcn_mfma_f32_16x16x32_bf16(Af[rp * 2 + ky], Bf[ky][nt], acc0[nt], 0, 0, 0);
          acc1[nt] = __builtin_amdgcn_mfma_f32_16x16x32_bf16(Af[rp * 2 + ky + 1], Bf[ky][nt], acc1[nt], 0, 0, 0);
        }
      }
#pragma unroll
      for (int nt = 0; nt < 2; ++nt) {
        const float bias = nt ? bias1 : bias0;
        const int co = nt * 16 + lx;
#pragma unroll
        for (int q = 0; q < 2; ++q) {
          const float m0 = fmaxf(acc0[nt][2 * q] + bias, 0.f);
          const float m1 = fmaxf(acc0[nt][2 * q + 1] + bias, 0.f);
          const float m2 = fmaxf(acc1[nt][2 * q] + bias, 0.f);
          const float m3 = fmaxf(acc1[nt][2 * q + 1] + bias, 0.f);
          const float mx = fmaxf(fmaxf(m0, m1), fmaxf(m2, m3));
          if (nt) msum1 += mx; else msum0 += mx;
          const int pcol = txi * 32 + xt * 8 + lg * 2 + q;
          p1b[(((size_t)b * 64 + prow) * 64 + pcol) * 32 + co] = f2bf(mx);
        }
      }
    }
  }

  msum0 += __shfl_xor(msum0, 16, 64);
  msum0 += __shfl_xor(msum0, 32, 64);
  msum1 += __shfl_xor(msum1, 16, 64);
  msum1 += __shfl_xor(msum1, 32, 64);
  if (lg == 0) {
    mred[w][lx] = msum0;
    mred[w][16 + lx] = msum1;
  }
  __syncthreads();
  if (tid < 32) {
    part_m1[(size_t)bid * 32 + tid] =
        mred[0][tid] + mred[1][tid] + mred[2][tid] + mred[3][tid];
  }
}

// ------------- K: SE1 + route2 + build k2' bf16 [b][tap][co][ci] (192 blocks) --
__global__ void k_buildk2(const float* __restrict__ part_m1,
                          const float* __restrict__ experts2,
                          const float* __restrict__ rw, const float* __restrict__ rb,
                          const float* __restrict__ w1, const float* __restrict__ w2,
                          const float* __restrict__ gamma, const float* __restrict__ var,
                          ushort_t* __restrict__ k2pb) {
  const int b = blockIdx.x / 3;
  const int seg = blockIdx.x - b * 3;
  const int tid = threadIdx.x;
  __shared__ float m1[32], h[2], s1[32], route[3];
  if (tid < 32) {
    float s = 0.f;
#pragma unroll
    for (int k = 0; k < 8; ++k) s += part_m1[(size_t)(b * 8 + k) * 32 + tid];
    m1[tid] = s * (1.0f / 4096.0f);
  }
  __syncthreads();
  if (tid < 2) {
    float z = 0.f;
    for (int c = 0; c < 32; ++c) z += m1[c] * w1[c * 2 + tid];
    h[tid] = fmaxf(z, 0.f);
  }
  __syncthreads();
  if (tid < 32) s1[tid] = sigmoidf_(h[0] * w2[tid] + h[1] * w2[32 + tid]);
  __syncthreads();
  if (tid < 3) {
    float z = rb[tid];
    for (int c = 0; c < 32; ++c) z += m1[c] * s1[c] * rw[c * 3 + tid];
    route[tid] = sigmoidf_(z);
  }
  __syncthreads();
  const float r0 = route[0], r1 = route[1], r2 = route[2];
  const int t_lo = seg * 6144, t_hi = t_lo + 6144;
  for (int t = t_lo + tid; t < t_hi; t += 256) {
    const int co = t & 63;
    const int ci = (t >> 6) & 31;
    const int tap = t >> 11;
    const float inv = gamma[co] * rsqrtf(var[co] + EPSBN);
    const float v = r0 * experts2[t] + r1 * experts2[18432 + t] + r2 * experts2[2 * 18432 + t];
    k2pb[(size_t)b * 18432 + ((size_t)tap * 64 + co) * 32 + ci] = f2bf(v * s1[ci] * inv);
  }
}

// ------------- K: conv2 MFMA (all 64 co per block, B streamed in halves) -------
// grid: 64 b x 16 tiles = 1024 blocks. Emits 9 boundary aggregates x 64 co.
__global__ __launch_bounds__(256)
void k_conv2(const ushort_t* __restrict__ p1b, const ushort_t* __restrict__ k2pb,
             const float* __restrict__ gamma, const float* __restrict__ beta,
             const float* __restrict__ bnmean, const float* __restrict__ bnvar,
             float* __restrict__ part_s3) {
  const int bi = blockIdx.x;
  const int b = bi >> 4;
  const int tile = bi & 15;
  const int ty = tile >> 2, tx2 = tile & 3;
  __shared__ __align__(16) short smem[24480];  // As 12960 + Bs 11520 shorts
  short* As = smem;
  short* Bs = smem + 12960;
  const int tid = threadIdx.x;

  const ushort_t* pb = p1b + (size_t)b * 131072;
  for (int v = tid; v < 1296; v += 256) {
    const int cell = v >> 2, part = v & 3;
    const int ly = cell / 18, lx2 = cell - ly * 18;
    const int gy = ty * 16 - 1 + ly, gx = tx2 * 16 - 1 + lx2;
    uint4 d = make_uint4(0u, 0u, 0u, 0u);
    if (((unsigned)gy < 64u) && ((unsigned)gx < 64u))
      d = *(const uint4*)(pb + (((size_t)gy << 6) + gx) * 32 + part * 8);
    *(uint4*)(As + (ly * 18 + lx2) * 40 + part * 8) = d;
  }

  const int w = tid >> 6;
  const int lane = tid & 63;
  const int lx = lane & 15, lg = lane >> 4;

  f4 acc[4][4];
#pragma unroll
  for (int mt = 0; mt < 4; ++mt)
#pragma unroll
    for (int nt = 0; nt < 4; ++nt)
      acc[mt][nt] = (f4){0.f, 0.f, 0.f, 0.f};

  // stream B through LDS in two cog halves; As resident throughout
  for (int hb = 0; hb < 2; ++hb) {
    if (hb) __syncthreads();  // protect Bs before overwrite
    for (int v = tid; v < 1152; v += 256) {
      const int r = v >> 2, part = v & 3;
      const int t = r >> 5, n = r & 31;
      const uint4 d = *(const uint4*)(k2pb + (size_t)b * 18432 +
                                      ((size_t)(t * 64 + hb * 32 + n)) * 32 + part * 8);
      *(uint4*)(Bs + r * 40 + part * 8) = d;
    }
    __syncthreads();

#pragma unroll
    for (int kx = 0; kx < 3; ++kx) {
      bf8 Af[6];
#pragma unroll
      for (int r = 0; r < 6; ++r)
        Af[r] = *(const bf8*)(As + ((4 * w + r) * 18 + lx + kx) * 40 + (lg << 3));
#pragma unroll
      for (int ky = 0; ky < 3; ++ky) {
        const int t = ky * 3 + kx;
        const bf8 Bf0 = *(const bf8*)(Bs + ((t << 5) + lx) * 40 + (lg << 3));
        const bf8 Bf1 = *(const bf8*)(Bs + ((t << 5) + 16 + lx) * 40 + (lg << 3));
#pragma unroll
        for (int mt = 0; mt < 4; ++mt) {
          acc[mt][hb * 2 + 0] = __builtin_amdgcn_mfma_f32_16x16x32_bf16(Af[ky + mt], Bf0, acc[mt][hb * 2 + 0], 0, 0, 0);
          acc[mt][hb * 2 + 1] = __builtin_amdgcn_mfma_f32_16x16x32_bf16(Af[ky + mt], Bf1, acc[mt][hb * 2 + 1], 0, 0, 0);
        }
      }
    }
  }

  // epilogue: BN + relu + pool + 9 boundary aggregates for all 64 co
  float inv[4], bias[4];
#pragma unroll
  for (int nt = 0; nt < 4; ++nt) {
    const int co = nt * 16 + lx;
    inv[nt] = gamma[co] * rsqrtf(bnvar[co] + EPSBN);
    bias[nt] = beta[co] - bnmean[co] * inv[nt];
  }
  float agg[4][9];
#pragma unroll
  for (int nt = 0; nt < 4; ++nt)
#pragma unroll
    for (int a = 0; a < 9; ++a) agg[nt][a] = 0.f;

#pragma unroll
  for (int half = 0; half < 2; ++half) {
    const int prow = ty * 8 + 2 * w + half;
    const bool rT = (prow == 0), rB = (prow == 31);
#pragma unroll
    for (int q = 0; q < 2; ++q) {
      const int pcol = tx2 * 8 + 2 * lg + q;
      const bool cL = (pcol == 0), cR = (pcol == 31);
#pragma unroll
      for (int nt = 0; nt < 4; ++nt) {
        const float m0 = fmaxf(acc[2 * half][nt][2 * q] + bias[nt], 0.f);
        const float m1 = fmaxf(acc[2 * half][nt][2 * q + 1] + bias[nt], 0.f);
        const float m2 = fmaxf(acc[2 * half + 1][nt][2 * q] + bias[nt], 0.f);
        const float m3 = fmaxf(acc[2 * half + 1][nt][2 * q + 1] + bias[nt], 0.f);
        const float mx = fmaxf(fmaxf(m0, m1), fmaxf(m2, m3));
        agg[nt][0] += mx;
        if (rT) agg[nt][1] += mx;
        if (rB) agg[nt][2] += mx;
        if (cL) agg[nt][3] += mx;
        if (cR) agg[nt][4] += mx;
        if (rT && cL) agg[nt][5] += mx;
        if (rT && cR) agg[nt][6] += mx;
        if (rB && cL) agg[nt][7] += mx;
        if (rB && cR) agg[nt][8] += mx;
      }
    }
  }

#pragma unroll
  for (int nt = 0; nt < 4; ++nt)
#pragma unroll
    for (int a = 0; a < 9; ++a) {
      float v = agg[nt][a];
      v += __shfl_xor(v, 16, 64);
      v += __shfl_xor(v, 32, 64);
      agg[nt][a] = v;
    }
  __syncthreads();  // done with As/Bs; reuse for reduction
  float* sred = (float*)smem;  // [w][nt][lx][a] = [4][4][16][9] = 2304 floats
  if (lg == 0) {
#pragma unroll
    for (int nt = 0; nt < 4; ++nt)
#pragma unroll
      for (int a = 0; a < 9; ++a)
        sred[((w * 4 + nt) * 16 + lx) * 9 + a] = agg[nt][a];
  }
  __syncthreads();
  for (int v = tid; v < 576; v += 256) {
    const int a = v >> 6;          // aggregate 0..8
    const int co = v & 63;
    const int nt = co >> 4, lxx = co & 15;
    float s = 0.f;
#pragma unroll
    for (int ww = 0; ww < 4; ++ww) s += sred[((ww * 4 + nt) * 16 + lxx) * 9 + a];
    part_s3[(size_t)bi * 576 + v] = s;
  }
}

// ------------- K: S3 reconstruct + SE2 + route3 + contraction + BN3 ------------
__global__ __launch_bounds__(512)
void k_final(const float* __restrict__ part_s3, const float* __restrict__ experts3,
             const float* __restrict__ rw, const float* __restrict__ rb,
             const float* __restrict__ w1, const float* __restrict__ w2,
             const float* __restrict__ gamma, const float* __restrict__ beta,
             const float* __restrict__ bnmean, const float* __restrict__ bnvar,
             float* __restrict__ out) {
  const int b = blockIdx.x;
  const int tid = threadIdx.x;
  __shared__ float AG[9][64], Sp[9][64], m2[64], h[4], s2[64], route[3], redf[4][128];

  for (int v = tid; v < 576; v += 512) {
    float s = 0.f;
#pragma unroll
    for (int tile = 0; tile < 16; ++tile)
      s += part_s3[(size_t)(b * 16 + tile) * 576 + v];
    AG[v >> 6][v & 63] = s;
  }
  __syncthreads();
  if (tid < 64) m2[tid] = AG[0][tid] * (1.0f / 1024.0f);
  __syncthreads();
  if (tid < 4) {
    float z = 0.f;
    for (int c = 0; c < 64; ++c) z += m2[c] * w1[c * 4 + tid];
    h[tid] = fmaxf(z, 0.f);
  }
  __syncthreads();
  if (tid < 64) {
    float z = 0.f;
#pragma unroll
    for (int j = 0; j < 4; ++j) z += h[j] * w2[j * 64 + tid];
    s2[tid] = sigmoidf_(z);
  }
  __syncthreads();
  if (tid < 3) {
    float z = rb[tid];
    for (int c = 0; c < 64; ++c) z += m2[c] * s2[c] * rw[c * 3 + tid];
    route[tid] = sigmoidf_(z);
  }
  __syncthreads();
  for (int v = tid; v < 576; v += 512) {
    const int tap = v >> 6, ci = v & 63;
    const int ky = tap / 3, kx = tap - 3 * ky;
    const float T = AG[0][ci];
    const float A = (ky == 0) ? AG[2][ci] : ((ky == 2) ? AG[1][ci] : 0.f);
    const float B = (kx == 0) ? AG[4][ci] : ((kx == 2) ? AG[3][ci] : 0.f);
    float AB = 0.f;
    if (ky == 0 && kx == 0) AB = AG[8][ci];
    else if (ky == 0 && kx == 2) AB = AG[7][ci];
    else if (ky == 2 && kx == 0) AB = AG[6][ci];
    else if (ky == 2 && kx == 2) AB = AG[5][ci];
    Sp[tap][ci] = (T - A - B + AB) * s2[ci];
  }
  __syncthreads();

  const int co = tid & 127;
  const int quarter = tid >> 7;
  const int tap_lo = (quarter == 0) ? 0 : (2 * quarter + 1);
  const int tap_hi = tap_lo + ((quarter == 0) ? 3 : 2);
  float acc = 0.f;
#pragma unroll
  for (int e = 0; e < 3; ++e) {
    float m = 0.f;
    for (int tap = tap_lo; tap < tap_hi; ++tap) {
      const float* E = experts3 + ((size_t)(e * 9 + tap) * 64) * 128 + co;
#pragma unroll 16
      for (int ci = 0; ci < 64; ++ci) m = fmaf(E[(size_t)ci * 128], Sp[tap][ci], m);
    }
    acc += route[e] * m;
  }
  redf[quarter][co] = acc;
  __syncthreads();
  if (tid < 128) {
    const float total = redf[0][tid] + redf[1][tid] + redf[2][tid] + redf[3][tid];
    const float inv = gamma[tid] * rsqrtf(bnvar[tid] + EPSBN);
    out[(size_t)b * 128 + tid] = total * (1.0f / 1024.0f) * inv + (beta[tid] - bnmean[tid] * inv);
  }
}

extern "C" void kernel_launch(void* const* d_in, const int* in_sizes, int n_in,
                              void* d_out, int out_size, void* d_ws, size_t ws_size,
                              hipStream_t stream) {
  const float* x        = (const float*)d_in[0];
  const float* experts1 = (const float*)d_in[1];
  const float* rw1      = (const float*)d_in[2];
  const float* rb1      = (const float*)d_in[3];
  const float* g1  = (const float*)d_in[4];
  const float* be1 = (const float*)d_in[5];
  const float* mu1 = (const float*)d_in[6];
  const float* va1 = (const float*)d_in[7];
  const float* sw1a = (const float*)d_in[8];
  const float* sw1b = (const float*)d_in[9];
  const float* experts2 = (const float*)d_in[10];
  const float* rw2 = (const float*)d_in[11];
  const float* rb2 = (const float*)d_in[12];
  const float* g2  = (const float*)d_in[13];
  const float* be2 = (const float*)d_in[14];
  const float* mu2 = (const float*)d_in[15];
  const float* va2 = (const float*)d_in[16];
  const float* sw2a = (const float*)d_in[17];
  const float* sw2b = (const float*)d_in[18];
  const float* experts3 = (const float*)d_in[19];
  const float* rw3 = (const float*)d_in[20];
  const float* rb3 = (const float*)d_in[21];
  const float* g3  = (const float*)d_in[22];
  const float* be3 = (const float*)d_in[23];
  const float* mu3 = (const float*)d_in[24];
  const float* va3 = (const float*)d_in[25];
  float* out = (float*)d_out;
  float* ws = (float*)d_ws;

  // workspace layout (float offsets, all 16B-aligned):
  float* meanx_part = ws;                           // 1536   [256][6]
  float* part_m1    = ws + 1536;                    // 16384  [512][32]
  ushort_t* k2pb    = (ushort_t*)(ws + 17920);      // 1,179,648 shorts = 589,824 fl
  float* part_s3    = ws + 607744;                  // 589,824  [1024][576]
  ushort_t* p1b     = (ushort_t*)(ws + 1197568);    // 8,388,608 shorts = 4,194,304 fl
  // end: 5,391,872 floats = 21.6 MB

  hipLaunchKernelGGL(k_mean_x, dim3(256), dim3(256), 0, stream, x, meanx_part);
  hipLaunchKernelGGL(k_conv1, dim3(512), dim3(256), 0, stream,
                     x, meanx_part, experts1, rw1, rb1, g1, be1, mu1, va1, p1b, part_m1);
  hipLaunchKernelGGL(k_buildk2, dim3(192), dim3(256), 0, stream,
                     part_m1, experts2, rw2, rb2, sw1a, sw1b, g2, va2, k2pb);
  hipLaunchKernelGGL(k_conv2, dim3(1024), dim3(256), 0, stream,
                     p1b, k2pb, g2, be2, mu2, va2, part_s3);
  hipLaunchKernelGGL(k_final, dim3(64), dim3(512), 0, stream,
                     part_s3, experts3, rw3, rb3, sw2a, sw2b, g3, be3, mu3, va3, out);
}